// Round 2
// baseline (272.303 us; speedup 1.0000x reference)
//
#include <hip/hip_runtime.h>

// Problem constants
#define NUM_EMB 1024
#define EMB_DIM 256
#define BATCH   32
#define HW      1024
#define Z_ELEMS (BATCH*EMB_DIM*HW)   // 8388608
#define LOSS_OFF Z_ELEMS
#define IDX_OFF (Z_ELEMS+1)

// ws: float[0] loss acc, uint[1] ticket, [16..1040) cnorm, [2048..34816) znorm
#define WS_CNORM_OFF 16
#define WS_ZNORM_OFF 2048

// out z-region scratch (all overwritten by k_gather at the very end):
//  halves [0 .. 524288)        : Bt — codebook*1024 as fp16, MFMA-B-frag tiled (512 KB)
//  ints   [262144 .. 294912)   : cand_cnt[32768]  (0 = resolved, 1025 = overflow)
//  ints   [294912 .. 1343488)  : cand_idx[32768][32] compacted survivors
//  floats [2392064 .. 2424832) : s1z[32768] = sum_d|z_d|
//  halves [6291456 .. 14680064): z16 — z as fp16, MFMA-A-frag tiled
#define CNT_IOFF  262144
#define CAND_IOFF 294912
#define S1Z_FOFF  2392064
#define Z16_HOFF  6291456
#define CAND_CAP  32

// Per-query filter threshold: T = T_SLOPE*S1z + T_BIAS (proof in round-1 notes:
// fp16 single pass, codebook scaled x1024 => need 3.82e-6*S1z + 1e-4; chosen
// slope/bias give 1.57x / 3x margin). Unchanged from the passing version.
#define T_SLOPE 6.0e-6f
#define T_BIAS  3.0e-4f

typedef __attribute__((ext_vector_type(8))) _Float16 f16x8;
typedef __attribute__((ext_vector_type(4))) float f32x4;

// ---------------------------------------------------------------------------
// K0: fused prep, 260 blocks.
//  blk 0..3     cnorm[k] via exact pairwise tree
//  blk 4..131   znorm[n] exact tree + S1z[n] + z -> fp16 A-fragment tiles
//  blk 132..259 pack codebook*1024 -> fp16 Bt in MFMA B-fragment order
// (cand_cnt zeroing removed: k_filter now writes counts directly, no atomics)
__global__ __launch_bounds__(256) void k_prep(const float* __restrict__ z,
                                              const float* __restrict__ cb,
                                              float* __restrict__ ws,
                                              float* __restrict__ out) {
    const int tid = threadIdx.x;
    const int blk = blockIdx.x;
    if (blk == 0 && tid == 0) { ws[0] = 0.0f; ((unsigned*)ws)[1] = 0u; }
    if (blk < 4) {
        int k = blk * 256 + tid;
        const float* row = cb + (size_t)k * EMB_DIM;
        float hsum[2];
#pragma unroll
        for (int h = 0; h < 2; ++h) {
            const float* a = row + h * 128;
            float r[8];
#pragma unroll
            for (int j = 0; j < 8; ++j) r[j] = __fmul_rn(a[j], a[j]);
            for (int i = 8; i < 128; i += 8)
#pragma unroll
                for (int j = 0; j < 8; ++j)
                    r[j] = __fadd_rn(r[j], __fmul_rn(a[i + j], a[i + j]));
            hsum[h] = __fadd_rn(__fadd_rn(__fadd_rn(r[0], r[1]), __fadd_rn(r[2], r[3])),
                                __fadd_rn(__fadd_rn(r[4], r[5]), __fadd_rn(r[6], r[7])));
        }
        ws[WS_CNORM_OFF + k] = __fadd_rn(hsum[0], hsum[1]);
    } else if (blk < 132) {
        int n = (blk - 4) * 256 + tid;
        int b = n >> 10, p = n & 1023;
        const float* base = z + (size_t)b * EMB_DIM * HW + p;
        _Float16* z16 = (_Float16*)out + Z16_HOFF;
        const int qb = n >> 6, r0 = n & 63;
        const int mt = r0 >> 4, l0 = r0 & 15;
        const size_t tb = (size_t)qb * 2048;      // f16x8 slots per query-block
        float hsum[2];
        float s1 = 0.0f;
#pragma unroll
        for (int h = 0; h < 2; ++h) {
            float racc[8], v[8];
#pragma unroll
            for (int j = 0; j < 8; ++j) v[j] = base[(size_t)(h * 128 + j) * HW];
            {
                int d0 = h * 128;
                int c = d0 >> 5, kh = (d0 >> 3) & 3;
                f16x8 g;
#pragma unroll
                for (int j = 0; j < 8; ++j) g[j] = (_Float16)v[j];
                *(f16x8*)(z16 + (tb + (size_t)(c * 4 + mt) * 64 + kh * 16 + l0) * 8) = g;
            }
#pragma unroll
            for (int j = 0; j < 8; ++j) { racc[j] = __fmul_rn(v[j], v[j]); s1 += fabsf(v[j]); }
            for (int i = 8; i < 128; i += 8) {
#pragma unroll
                for (int j = 0; j < 8; ++j) v[j] = base[(size_t)(h * 128 + i + j) * HW];
                int d0 = h * 128 + i;
                int c = d0 >> 5, kh = (d0 >> 3) & 3;
                f16x8 g;
#pragma unroll
                for (int j = 0; j < 8; ++j) g[j] = (_Float16)v[j];
                *(f16x8*)(z16 + (tb + (size_t)(c * 4 + mt) * 64 + kh * 16 + l0) * 8) = g;
#pragma unroll
                for (int j = 0; j < 8; ++j) {
                    racc[j] = __fadd_rn(racc[j], __fmul_rn(v[j], v[j]));
                    s1 += fabsf(v[j]);
                }
            }
            hsum[h] = __fadd_rn(__fadd_rn(__fadd_rn(racc[0], racc[1]), __fadd_rn(racc[2], racc[3])),
                                __fadd_rn(__fadd_rn(racc[4], racc[5]), __fadd_rn(racc[6], racc[7])));
        }
        ws[WS_ZNORM_OFF + n] = __fadd_rn(hsum[0], hsum[1]);
        out[S1Z_FOFF + n] = s1;
    } else {
        unsigned u = (unsigned)(blk - 132) * 256 + tid;   // 0..32767
        int lane = u & 63;
        int nt   = (u >> 6) & 15;
        int cc   = (u >> 10) & 7;
        int s    = (u >> 13) & 3;
        int code = s * 256 + nt * 16 + (lane & 15);
        int d0   = cc * 32 + (lane >> 4) * 8;
        const float* cr = cb + (size_t)code * EMB_DIM + d0;
        f16x8 v;
#pragma unroll
        for (int j = 0; j < 8; ++j) v[j] = (_Float16)(cr[j] * 1024.0f);
        _Float16* Bt = (_Float16*)out;
        *(f16x8*)(Bt + ((((size_t)(s * 8 + cc) * 16 + nt) * 64 + lane) * 8)) = v;
    }
}

// ---------------------------------------------------------------------------
// K1: MFMA candidate filter, all 4 slabs per block.
//  - A tile (64 queries x 256 dims fp16 = 32 KB) staged to LDS ONCE, read as
//    conflict-free ds_read_b128 (A frags are identical across the 4 waves).
//  - B frags per-lane from global (L2-hot 512 KB), 3-buffer depth-2 prefetch.
//  - Per slab: sv = c2 - 2*dot, slab min -> running min, append (k,sv) to LDS
//    candidate buffer under running-min+T (superset of final set: running min
//    only decreases, so any candidate within final_min+T is appended when its
//    slab is processed).
//  - Final: prune with global min+T; single survivor -> write index directly
//    (cnt=0); else compacted list + cnt; overflow (>32) -> cnt=1025 sentinel.
// No global atomics anywhere.
__global__ __launch_bounds__(256, 3) void k_filter(const float* __restrict__ ws,
                                                   float* __restrict__ out) {
    __shared__ __attribute__((aligned(16))) _Float16 A_lds[2048 * 8];  // 32 KB
    __shared__ float wm[256];
    __shared__ float rmin_s[64];
    __shared__ float tq_s[64];
    __shared__ float thr_s[64];
    __shared__ int   cnt_s[64];
    __shared__ int   bidx_s[64][CAND_CAP];   // 8 KB
    __shared__ float bval_s[64][CAND_CAP];   // 8 KB

    const int tid = threadIdx.x;
    const int w = tid >> 6, l = tid & 63;
    const int qb = blockIdx.x, nq0 = qb * 64;

    const f16x8* B8 = (const f16x8*)out;
    const f16x8* Ag = (const f16x8*)((const _Float16*)out + Z16_HOFF) + (size_t)qb * 2048;
    f16x8* Al = (f16x8*)A_lds;

    // prologue: issue B loads for steps 0,1 before A staging so they overlap
    f16x8 b[3][4];
#pragma unroll
    for (int t = 0; t < 2; ++t)
#pragma unroll
        for (int nt = 0; nt < 4; ++nt)
            b[t][nt] = B8[((size_t)(t * 16) + w * 4 + nt) * 64 + l];
    // stage A tile (linear copy, one barrier, no per-chunk barriers after)
#pragma unroll
    for (int i = 0; i < 8; ++i) Al[i * 256 + tid] = Ag[i * 256 + tid];
    if (tid < 64) {
        cnt_s[tid] = 0;
        rmin_s[tid] = 3.4e38f;
        tq_s[tid] = fmaf(T_SLOPE, out[S1Z_FOFF + nq0 + tid], T_BIAS);
    }
    __syncthreads();

    const float* cn = ws + WS_CNORM_OFF;
    f32x4 acc[4][4];
#pragma unroll
    for (int mt = 0; mt < 4; ++mt)
#pragma unroll
        for (int nt = 0; nt < 4; ++nt) acc[mt][nt] = (f32x4)(0.0f);

#pragma unroll
    for (int t = 0; t < 32; ++t) {           // t = slab*8 + chunk
        const int c = t & 7, s = t >> 3;
        if (t + 2 < 32) {                    // depth-2 B prefetch
            const int t2 = t + 2;
#pragma unroll
            for (int nt = 0; nt < 4; ++nt)
                b[t2 % 3][nt] = B8[((size_t)(t2 * 16) + w * 4 + nt) * 64 + l];
        }
#pragma unroll
        for (int mt = 0; mt < 4; ++mt) {
            f16x8 av = Al[(c * 4 + mt) * 64 + l];
#pragma unroll
            for (int nt = 0; nt < 4; ++nt)
                acc[mt][nt] = __builtin_amdgcn_mfma_f32_16x16x32_f16(av, b[t % 3][nt], acc[mt][nt], 0, 0, 0);
        }
        if (c == 7) {
            // ---- slab epilogue (B loads for next slab already in flight) ----
            float c2[4];
#pragma unroll
            for (int nt = 0; nt < 4; ++nt)
                c2[nt] = cn[s * 256 + (w * 4 + nt) * 16 + (l & 15)];
            float vmin[4][4];
#pragma unroll
            for (int mt = 0; mt < 4; ++mt)
#pragma unroll
                for (int reg = 0; reg < 4; ++reg) vmin[mt][reg] = 3.4e38f;
#pragma unroll
            for (int mt = 0; mt < 4; ++mt)
#pragma unroll
                for (int nt = 0; nt < 4; ++nt)
#pragma unroll
                    for (int reg = 0; reg < 4; ++reg) {
                        float sv = fmaf(-0.001953125f, acc[mt][nt][reg], c2[nt]);  // -2/1024
                        acc[mt][nt][reg] = sv;
                        vmin[mt][reg] = fminf(vmin[mt][reg], sv);
                    }
#pragma unroll
            for (int msk = 1; msk < 16; msk <<= 1)
#pragma unroll
                for (int mt = 0; mt < 4; ++mt)
#pragma unroll
                    for (int reg = 0; reg < 4; ++reg)
                        vmin[mt][reg] = fminf(vmin[mt][reg], __shfl_xor(vmin[mt][reg], msk, 64));
            if ((l & 15) == 0) {
#pragma unroll
                for (int mt = 0; mt < 4; ++mt)
#pragma unroll
                    for (int reg = 0; reg < 4; ++reg)
                        wm[w * 64 + mt * 16 + (l >> 4) * 4 + reg] = vmin[mt][reg];
            }
            __syncthreads();
            if (tid < 64) {
                float smin = fminf(fminf(wm[tid], wm[64 + tid]),
                                   fminf(wm[128 + tid], wm[192 + tid]));
                float rm = fminf(rmin_s[tid], smin);
                rmin_s[tid] = rm;
                thr_s[tid] = rm + tq_s[tid];
            }
            __syncthreads();
            // append candidates under running threshold
#pragma unroll
            for (int mt = 0; mt < 4; ++mt)
#pragma unroll
                for (int reg = 0; reg < 4; ++reg) {
                    int m = mt * 16 + (l >> 4) * 4 + reg;
                    float th = thr_s[m];
#pragma unroll
                    for (int nt = 0; nt < 4; ++nt) {
                        float sv = acc[mt][nt][reg];
                        if (sv <= th) {
                            int kg = s * 256 + (w * 4 + nt) * 16 + (l & 15);
                            int pos = atomicAdd(&cnt_s[m], 1);
                            if (pos < CAND_CAP) { bidx_s[m][pos] = kg; bval_s[m][pos] = sv; }
                        }
                    }
                }
            // re-zero accumulators for next slab
#pragma unroll
            for (int mt = 0; mt < 4; ++mt)
#pragma unroll
                for (int nt = 0; nt < 4; ++nt) acc[mt][nt] = (f32x4)(0.0f);
        }
    }
    __syncthreads();   // all appends visible
    if (tid < 64) {
        int n = nq0 + tid;
        int c = cnt_s[tid];
        int* cnt_g  = (int*)out + CNT_IOFF;
        int* cand_g = (int*)out + CAND_IOFF;
        if (c > CAND_CAP) {
            cnt_g[n] = 1025;                  // overflow sentinel -> full rescan
        } else {
            float th = thr_s[tid];            // global min + T (after slab 3)
            int m = 0, keep = 0;
            for (int j = 0; j < c; ++j) {
                if (bval_s[tid][j] <= th) {
                    cand_g[(size_t)n * CAND_CAP + m] = bidx_s[tid][j];
                    if (m == 0) keep = bidx_s[tid][j];
                    ++m;
                }
            }
            if (m == 1) {
                out[IDX_OFF + n] = (float)keep;   // resolved here
                cnt_g[n] = 0;
            } else {
                cnt_g[n] = m;
            }
        }
    }
}

// ---------------------------------------------------------------------------
// K2: wave-parallel exact rescore. 512 blocks x 256 thr (8 waves/CU). Each
// wave owns 16 queries; pruned survivors map one-per-lane; each lane runs the
// bit-proven reference recipe (serial ascending-d fma dot, fold
// fl(fl(z2+c2) - fl(2*dot))); (sv,k) min-first-index shuffle reduction
// reproduces the first-index tie rule. z column loads are wave-broadcast.
__global__ __launch_bounds__(256) void k_rescore(const float* __restrict__ z,
                                                 const float* __restrict__ cb,
                                                 const float* __restrict__ ws,
                                                 float* __restrict__ out) {
    const int tid = threadIdx.x;
    const int w = tid >> 6, l = tid & 63;
    const int n0 = blockIdx.x * 64 + w * 16;
    const int* cnt  = (const int*)out + CNT_IOFF;
    const int* cand = (const int*)out + CAND_IOFF;
    const float* cn = ws + WS_CNORM_OFF;

    int cpre = (l < 16) ? cnt[n0 + l] : 0;
#pragma unroll 1
    for (int i = 0; i < 16; ++i) {
        int c = __shfl(cpre, i, 64);          // uniform across wave
        if (c == 0) continue;                 // resolved by k_filter
        int n = n0 + i;
        int b = n >> 10, p = n & 1023;
        const float* zc = z + (size_t)b * EMB_DIM * HW + p;
        float z2 = ws[WS_ZNORM_OFF + n];
        float sv; int kk;
        if (c <= CAND_CAP) {
            kk = (l < c) ? cand[(size_t)n * CAND_CAP + l] : 0;
            const float* r = cb + (size_t)kk * EMB_DIM;
            float dot = 0.0f;
#pragma unroll 8
            for (int d = 0; d < EMB_DIM; ++d)
                dot = fmaf(zc[(size_t)d * HW], r[d], dot);
            float t1 = __fadd_rn(z2, cn[kk]);
            sv = __fadd_rn(t1, __fmul_rn(-2.0f, dot));
            if (l >= c) { sv = 3.4e38f; kk = NUM_EMB; }
        } else {                              // overflow: distributed full scan
            sv = 3.4e38f; kk = NUM_EMB;
            for (int k0 = l; k0 < NUM_EMB; k0 += 64) {
                const float* r = cb + (size_t)k0 * EMB_DIM;
                float dot = 0.0f;
#pragma unroll 8
                for (int d = 0; d < EMB_DIM; ++d)
                    dot = fmaf(zc[(size_t)d * HW], r[d], dot);
                float t1 = __fadd_rn(z2, cn[k0]);
                float s2 = __fadd_rn(t1, __fmul_rn(-2.0f, dot));
                if (s2 < sv) { sv = s2; kk = k0; }   // ascending k: < keeps first
            }
        }
#pragma unroll
        for (int off = 32; off; off >>= 1) {
            float osv = __shfl_xor(sv, off, 64);
            int   okk = __shfl_xor(kk, off, 64);
            if (osv < sv || (osv == sv && okk < kk)) { sv = osv; kk = okk; }
        }
        if (l == 0) out[IDX_OFF + n] = (float)kk;
    }
}

// ---------------------------------------------------------------------------
// K3: gather z_q via LDS-staged codebook rows, straight-through write
// out = fl(z + fl(z_q - z)), loss partials + fused final scale via ticket.
// (Arithmetic order untouched — bit-exact vs previous passing version.)
__global__ __launch_bounds__(256) void k_gather(const float* __restrict__ z,
                                                const float* __restrict__ cb,
                                                float* __restrict__ out,
                                                float* __restrict__ ws) {
    __shared__ float s_cb[64][65];
    __shared__ int   s_idx[64];
    __shared__ float s_red[4];
    const int tid = threadIdx.x;
    const int b  = blockIdx.x >> 4;
    const int p0 = (blockIdx.x & 15) * 64;

    if (tid < 64)
        s_idx[tid] = (int)out[IDX_OFF + (size_t)b * HW + p0 + tid];
    __syncthreads();

    const int p    = tid & 63;
    const int cgrp = tid >> 6;
    const int row  = tid >> 2;
    const int q4   = tid & 3;
    const float* zrow = z   + (size_t)b * EMB_DIM * HW + p0 + p;
    float*       orow = out + (size_t)b * EMB_DIM * HW + p0 + p;

    float acc = 0.0f;
#pragma unroll 1
    for (int d0 = 0; d0 < EMB_DIM; d0 += 64) {
        const float* cr = cb + (size_t)s_idx[row] * EMB_DIM + d0;
#pragma unroll
        for (int pass = 0; pass < 4; ++pass) {
            int c = q4 * 4 + pass * 16;
            *(float4*)(&s_cb[row][c]) = *(const float4*)(cr + c);
        }
        __syncthreads();
#pragma unroll
        for (int j = 0; j < 16; ++j) {
            int c = cgrp * 16 + j;
            float zq = s_cb[p][c];
            float zv = zrow[(size_t)(d0 + c) * HW];
            float d  = zq - zv;
            orow[(size_t)(d0 + c) * HW] = zv + d;
            acc += d * d;
        }
        __syncthreads();
    }
#pragma unroll
    for (int off = 32; off > 0; off >>= 1) acc += __shfl_down(acc, off, 64);
    if ((tid & 63) == 0) s_red[tid >> 6] = acc;
    __syncthreads();
    if (tid == 0) {
        atomicAdd(ws, s_red[0] + s_red[1] + s_red[2] + s_red[3]);
        __threadfence();
        unsigned old = atomicAdd((unsigned int*)ws + 1, 1u);
        if (old == 511u) {
            float total = atomicAdd(ws, 0.0f);
            out[LOSS_OFF] = 1.25f * (total * (1.0f / 8388608.0f));
        }
    }
}

// ---------------------------------------------------------------------------
extern "C" void kernel_launch(void* const* d_in, const int* in_sizes, int n_in,
                              void* d_out, int out_size, void* d_ws, size_t ws_size,
                              hipStream_t stream) {
    const float* z  = (const float*)d_in[0];
    const float* cb = (const float*)d_in[1];
    float* out = (float*)d_out;
    float* ws  = (float*)d_ws;

    k_prep   <<<260, 256, 0, stream>>>(z, cb, ws, out);
    k_filter <<<512, 256, 0, stream>>>(ws, out);
    k_rescore<<<512, 256, 0, stream>>>(z, cb, ws, out);
    k_gather <<<512, 256, 0, stream>>>(z, cb, out, ws);
}

// Round 3
// 186.726 us; speedup vs baseline: 1.4583x; 1.4583x over previous
//
#include <hip/hip_runtime.h>

// Problem constants
#define NUM_EMB 1024
#define EMB_DIM 256
#define BATCH   32
#define HW      1024
#define Z_ELEMS (BATCH*EMB_DIM*HW)   // 8388608
#define LOSS_OFF Z_ELEMS
#define IDX_OFF (Z_ELEMS+1)

// ws: float[0] loss acc, uint[1] ticket, [16..1040) cnorm, [2048..34816) znorm
#define WS_CNORM_OFF 16
#define WS_ZNORM_OFF 2048

// out z-region scratch (all overwritten by k_gather at the very end):
//  halves [0 .. 524288)        : Bt — codebook*1024 as fp16, MFMA-B-frag tiled (512 KB)
//  ints   [262144 .. 294912)   : cand_cnt[32768]  (0 = resolved, 1025 = overflow)
//  ints   [294912 .. 1343488)  : cand_idx[32768][32] compacted survivors
//  floats [2392064 .. 2424832) : s1z[32768] = sum_d|z_d|
//  halves [6291456 .. 14680064): z16 — z as fp16, MFMA-A-frag tiled
#define CNT_IOFF  262144
#define CAND_IOFF 294912
#define S1Z_FOFF  2392064
#define Z16_HOFF  6291456
#define CAND_CAP  32

// Per-query filter threshold: T = T_SLOPE*S1z + T_BIAS (proof in round-1 notes:
// fp16 single pass, codebook scaled x1024 => need 3.82e-6*S1z + 1e-4; chosen
// slope/bias give 1.57x / 3x margin). Unchanged from the passing version.
#define T_SLOPE 6.0e-6f
#define T_BIAS  3.0e-4f

typedef __attribute__((ext_vector_type(8))) _Float16 f16x8;
typedef __attribute__((ext_vector_type(4))) float f32x4;

// ---------------------------------------------------------------------------
// K0: fused prep, 260 blocks.  (unchanged from passing round-2 version)
__global__ __launch_bounds__(256) void k_prep(const float* __restrict__ z,
                                              const float* __restrict__ cb,
                                              float* __restrict__ ws,
                                              float* __restrict__ out) {
    const int tid = threadIdx.x;
    const int blk = blockIdx.x;
    if (blk == 0 && tid == 0) { ws[0] = 0.0f; ((unsigned*)ws)[1] = 0u; }
    if (blk < 4) {
        int k = blk * 256 + tid;
        const float* row = cb + (size_t)k * EMB_DIM;
        float hsum[2];
#pragma unroll
        for (int h = 0; h < 2; ++h) {
            const float* a = row + h * 128;
            float r[8];
#pragma unroll
            for (int j = 0; j < 8; ++j) r[j] = __fmul_rn(a[j], a[j]);
            for (int i = 8; i < 128; i += 8)
#pragma unroll
                for (int j = 0; j < 8; ++j)
                    r[j] = __fadd_rn(r[j], __fmul_rn(a[i + j], a[i + j]));
            hsum[h] = __fadd_rn(__fadd_rn(__fadd_rn(r[0], r[1]), __fadd_rn(r[2], r[3])),
                                __fadd_rn(__fadd_rn(r[4], r[5]), __fadd_rn(r[6], r[7])));
        }
        ws[WS_CNORM_OFF + k] = __fadd_rn(hsum[0], hsum[1]);
    } else if (blk < 132) {
        int n = (blk - 4) * 256 + tid;
        int b = n >> 10, p = n & 1023;
        const float* base = z + (size_t)b * EMB_DIM * HW + p;
        _Float16* z16 = (_Float16*)out + Z16_HOFF;
        const int qb = n >> 6, r0 = n & 63;
        const int mt = r0 >> 4, l0 = r0 & 15;
        const size_t tb = (size_t)qb * 2048;      // f16x8 slots per query-block
        float hsum[2];
        float s1 = 0.0f;
#pragma unroll
        for (int h = 0; h < 2; ++h) {
            float racc[8], v[8];
#pragma unroll
            for (int j = 0; j < 8; ++j) v[j] = base[(size_t)(h * 128 + j) * HW];
            {
                int d0 = h * 128;
                int c = d0 >> 5, kh = (d0 >> 3) & 3;
                f16x8 g;
#pragma unroll
                for (int j = 0; j < 8; ++j) g[j] = (_Float16)v[j];
                *(f16x8*)(z16 + (tb + (size_t)(c * 4 + mt) * 64 + kh * 16 + l0) * 8) = g;
            }
#pragma unroll
            for (int j = 0; j < 8; ++j) { racc[j] = __fmul_rn(v[j], v[j]); s1 += fabsf(v[j]); }
            for (int i = 8; i < 128; i += 8) {
#pragma unroll
                for (int j = 0; j < 8; ++j) v[j] = base[(size_t)(h * 128 + i + j) * HW];
                int d0 = h * 128 + i;
                int c = d0 >> 5, kh = (d0 >> 3) & 3;
                f16x8 g;
#pragma unroll
                for (int j = 0; j < 8; ++j) g[j] = (_Float16)v[j];
                *(f16x8*)(z16 + (tb + (size_t)(c * 4 + mt) * 64 + kh * 16 + l0) * 8) = g;
#pragma unroll
                for (int j = 0; j < 8; ++j) {
                    racc[j] = __fadd_rn(racc[j], __fmul_rn(v[j], v[j]));
                    s1 += fabsf(v[j]);
                }
            }
            hsum[h] = __fadd_rn(__fadd_rn(__fadd_rn(racc[0], racc[1]), __fadd_rn(racc[2], racc[3])),
                                __fadd_rn(__fadd_rn(racc[4], racc[5]), __fadd_rn(racc[6], racc[7])));
        }
        ws[WS_ZNORM_OFF + n] = __fadd_rn(hsum[0], hsum[1]);
        out[S1Z_FOFF + n] = s1;
    } else {
        unsigned u = (unsigned)(blk - 132) * 256 + tid;   // 0..32767
        int lane = u & 63;
        int nt   = (u >> 6) & 15;
        int cc   = (u >> 10) & 7;
        int s    = (u >> 13) & 3;
        int code = s * 256 + nt * 16 + (lane & 15);
        int d0   = cc * 32 + (lane >> 4) * 8;
        const float* cr = cb + (size_t)code * EMB_DIM + d0;
        f16x8 v;
#pragma unroll
        for (int j = 0; j < 8; ++j) v[j] = (_Float16)(cr[j] * 1024.0f);
        _Float16* Bt = (_Float16*)out;
        *(f16x8*)(Bt + ((((size_t)(s * 8 + cc) * 16 + nt) * 64 + lane) * 8)) = v;
    }
}

// ---------------------------------------------------------------------------
// K1: MFMA candidate filter, all 4 slabs per block. (unchanged, passing)
__global__ __launch_bounds__(256, 3) void k_filter(const float* __restrict__ ws,
                                                   float* __restrict__ out) {
    __shared__ __attribute__((aligned(16))) _Float16 A_lds[2048 * 8];  // 32 KB
    __shared__ float wm[256];
    __shared__ float rmin_s[64];
    __shared__ float tq_s[64];
    __shared__ float thr_s[64];
    __shared__ int   cnt_s[64];
    __shared__ int   bidx_s[64][CAND_CAP];   // 8 KB
    __shared__ float bval_s[64][CAND_CAP];   // 8 KB

    const int tid = threadIdx.x;
    const int w = tid >> 6, l = tid & 63;
    const int qb = blockIdx.x, nq0 = qb * 64;

    const f16x8* B8 = (const f16x8*)out;
    const f16x8* Ag = (const f16x8*)((const _Float16*)out + Z16_HOFF) + (size_t)qb * 2048;
    f16x8* Al = (f16x8*)A_lds;

    // prologue: issue B loads for steps 0,1 before A staging so they overlap
    f16x8 b[3][4];
#pragma unroll
    for (int t = 0; t < 2; ++t)
#pragma unroll
        for (int nt = 0; nt < 4; ++nt)
            b[t][nt] = B8[((size_t)(t * 16) + w * 4 + nt) * 64 + l];
    // stage A tile (linear copy, one barrier, no per-chunk barriers after)
#pragma unroll
    for (int i = 0; i < 8; ++i) Al[i * 256 + tid] = Ag[i * 256 + tid];
    if (tid < 64) {
        cnt_s[tid] = 0;
        rmin_s[tid] = 3.4e38f;
        tq_s[tid] = fmaf(T_SLOPE, out[S1Z_FOFF + nq0 + tid], T_BIAS);
    }
    __syncthreads();

    const float* cn = ws + WS_CNORM_OFF;
    f32x4 acc[4][4];
#pragma unroll
    for (int mt = 0; mt < 4; ++mt)
#pragma unroll
        for (int nt = 0; nt < 4; ++nt) acc[mt][nt] = (f32x4)(0.0f);

#pragma unroll
    for (int t = 0; t < 32; ++t) {           // t = slab*8 + chunk
        const int c = t & 7, s = t >> 3;
        if (t + 2 < 32) {                    // depth-2 B prefetch
            const int t2 = t + 2;
#pragma unroll
            for (int nt = 0; nt < 4; ++nt)
                b[t2 % 3][nt] = B8[((size_t)(t2 * 16) + w * 4 + nt) * 64 + l];
        }
#pragma unroll
        for (int mt = 0; mt < 4; ++mt) {
            f16x8 av = Al[(c * 4 + mt) * 64 + l];
#pragma unroll
            for (int nt = 0; nt < 4; ++nt)
                acc[mt][nt] = __builtin_amdgcn_mfma_f32_16x16x32_f16(av, b[t % 3][nt], acc[mt][nt], 0, 0, 0);
        }
        if (c == 7) {
            // ---- slab epilogue (B loads for next slab already in flight) ----
            float c2[4];
#pragma unroll
            for (int nt = 0; nt < 4; ++nt)
                c2[nt] = cn[s * 256 + (w * 4 + nt) * 16 + (l & 15)];
            float vmin[4][4];
#pragma unroll
            for (int mt = 0; mt < 4; ++mt)
#pragma unroll
                for (int reg = 0; reg < 4; ++reg) vmin[mt][reg] = 3.4e38f;
#pragma unroll
            for (int mt = 0; mt < 4; ++mt)
#pragma unroll
                for (int nt = 0; nt < 4; ++nt)
#pragma unroll
                    for (int reg = 0; reg < 4; ++reg) {
                        float sv = fmaf(-0.001953125f, acc[mt][nt][reg], c2[nt]);  // -2/1024
                        acc[mt][nt][reg] = sv;
                        vmin[mt][reg] = fminf(vmin[mt][reg], sv);
                    }
#pragma unroll
            for (int msk = 1; msk < 16; msk <<= 1)
#pragma unroll
                for (int mt = 0; mt < 4; ++mt)
#pragma unroll
                    for (int reg = 0; reg < 4; ++reg)
                        vmin[mt][reg] = fminf(vmin[mt][reg], __shfl_xor(vmin[mt][reg], msk, 64));
            if ((l & 15) == 0) {
#pragma unroll
                for (int mt = 0; mt < 4; ++mt)
#pragma unroll
                    for (int reg = 0; reg < 4; ++reg)
                        wm[w * 64 + mt * 16 + (l >> 4) * 4 + reg] = vmin[mt][reg];
            }
            __syncthreads();
            if (tid < 64) {
                float smin = fminf(fminf(wm[tid], wm[64 + tid]),
                                   fminf(wm[128 + tid], wm[192 + tid]));
                float rm = fminf(rmin_s[tid], smin);
                rmin_s[tid] = rm;
                thr_s[tid] = rm + tq_s[tid];
            }
            __syncthreads();
            // append candidates under running threshold
#pragma unroll
            for (int mt = 0; mt < 4; ++mt)
#pragma unroll
                for (int reg = 0; reg < 4; ++reg) {
                    int m = mt * 16 + (l >> 4) * 4 + reg;
                    float th = thr_s[m];
#pragma unroll
                    for (int nt = 0; nt < 4; ++nt) {
                        float sv = acc[mt][nt][reg];
                        if (sv <= th) {
                            int kg = s * 256 + (w * 4 + nt) * 16 + (l & 15);
                            int pos = atomicAdd(&cnt_s[m], 1);
                            if (pos < CAND_CAP) { bidx_s[m][pos] = kg; bval_s[m][pos] = sv; }
                        }
                    }
                }
            // re-zero accumulators for next slab
#pragma unroll
            for (int mt = 0; mt < 4; ++mt)
#pragma unroll
                for (int nt = 0; nt < 4; ++nt) acc[mt][nt] = (f32x4)(0.0f);
        }
    }
    __syncthreads();   // all appends visible
    if (tid < 64) {
        int n = nq0 + tid;
        int c = cnt_s[tid];
        int* cnt_g  = (int*)out + CNT_IOFF;
        int* cand_g = (int*)out + CAND_IOFF;
        if (c > CAND_CAP) {
            cnt_g[n] = 1025;                  // overflow sentinel -> full rescan
        } else {
            float th = thr_s[tid];            // global min + T (after slab 3)
            int m = 0, keep = 0;
            for (int j = 0; j < c; ++j) {
                if (bval_s[tid][j] <= th) {
                    cand_g[(size_t)n * CAND_CAP + m] = bidx_s[tid][j];
                    if (m == 0) keep = bidx_s[tid][j];
                    ++m;
                }
            }
            if (m == 1) {
                out[IDX_OFF + n] = (float)keep;   // resolved here
                cnt_g[n] = 0;
            } else {
                cnt_g[n] = m;
            }
        }
    }
}

// ---------------------------------------------------------------------------
// K2: exact rescore, candidate-per-thread with LDS-staged z tile.
// Block = 64 consecutive queries. z tile [256 d][64 q] fp32 staged coalesced
// (float4, exact bits). Block-wide candidate list built by wave-0 prefix scan;
// one candidate per thread runs the bit-proven recipe (serial ascending-d fma
// dot, fold fl(fl(z2+c2) - fl(2*dot))). Per-query argmin via order-preserving
// (enc(sv)<<32 | k) atomicMin in LDS == min sv then smallest k == reference
// first-index tie rule. Overflow sentinel -> 64-lane distributed full scan.
__global__ __launch_bounds__(256) void k_rescore(const float* __restrict__ z,
                                                 const float* __restrict__ cb,
                                                 const float* __restrict__ ws,
                                                 float* __restrict__ out) {
    __shared__ __attribute__((aligned(16))) float z_lds[256][64];   // 64 KB
    __shared__ int   c_s[64];
    __shared__ int   offI[64];
    __shared__ int   ovf_s[64];
    __shared__ unsigned long long key_s[64];
    __shared__ int   work_s;

    const int tid = threadIdx.x;
    const int w = tid >> 6, l = tid & 63;
    const int n0 = blockIdx.x * 64;
    const int b = n0 >> 10, p0 = n0 & 1023;
    const int* cnt  = (const int*)out + CNT_IOFF;
    const int* cand = (const int*)out + CAND_IOFF;
    const float* cn = ws + WS_CNORM_OFF;

    if (tid < 64) {
        int c = cnt[n0 + tid];
        int ov = (c > CAND_CAP) ? 1 : 0;
        ovf_s[tid] = ov;
        int cc = (ov || c < 2) ? 0 : c;
        c_s[tid] = cc;
        key_s[tid] = ~0ULL;
        int v = cc;
#pragma unroll
        for (int off = 1; off < 64; off <<= 1) {
            int u = __shfl_up(v, off, 64);
            if (l >= off) v += u;
        }
        offI[tid] = v;
        unsigned long long ball = __ballot(ov != 0);
        if (tid == 63) work_s = v + (ball ? 1 : 0);
    }
    __syncthreads();
    if (work_s == 0) return;    // whole block resolved by k_filter

    // stage z tile: [d][q] fp32, float4 coalesced (exact bits)
    {
        const float* zb = z + (size_t)b * EMB_DIM * HW + p0;
        const int q4 = tid & 15, g = tid >> 4;
#pragma unroll 4
        for (int r = 0; r < 16; ++r) {
            int d = r * 16 + g;
            float4 v = *(const float4*)(zb + (size_t)d * HW + q4 * 4);
            *(float4*)&z_lds[d][q4 * 4] = v;
        }
    }
    __syncthreads();

    // candidate-per-thread exact rescore
    const int C = offI[63];
    for (int t = tid; t < C; t += 256) {
        int lo = 0, hi = 63;
        while (lo < hi) { int mid = (lo + hi) >> 1; if (offI[mid] > t) hi = mid; else lo = mid + 1; }
        const int m = lo;
        const int j = t - (m ? offI[m - 1] : 0);
        const int n = n0 + m;
        const int kk = cand[(size_t)n * CAND_CAP + j];
        const float* r = cb + (size_t)kk * EMB_DIM;
        float dot = 0.0f;
#pragma unroll 8
        for (int d = 0; d < EMB_DIM; ++d)
            dot = fmaf(z_lds[d][m], r[d], dot);
        float t1 = __fadd_rn(ws[WS_ZNORM_OFF + n], cn[kk]);
        float sv = __fadd_rn(t1, __fmul_rn(-2.0f, dot));
        unsigned ue = __float_as_uint(sv);
        ue = (ue >> 31) ? ~ue : (ue | 0x80000000u);
        atomicMin(&key_s[m], ((unsigned long long)ue << 32) | (unsigned)kk);
    }

    // overflow queries (rare): distributed exact full scan, wave per query
    for (int m = w; m < 64; m += 4) {
        if (!ovf_s[m]) continue;
        const int n = n0 + m;
        const float z2 = ws[WS_ZNORM_OFF + n];
        float sv = 3.4e38f; int kk = NUM_EMB;
        for (int k0 = l; k0 < NUM_EMB; k0 += 64) {
            const float* r = cb + (size_t)k0 * EMB_DIM;
            float dot = 0.0f;
#pragma unroll 8
            for (int d = 0; d < EMB_DIM; ++d)
                dot = fmaf(z_lds[d][m], r[d], dot);
            float t1 = __fadd_rn(z2, cn[k0]);
            float s2 = __fadd_rn(t1, __fmul_rn(-2.0f, dot));
            if (s2 < sv) { sv = s2; kk = k0; }   // ascending k: < keeps first
        }
#pragma unroll
        for (int off = 32; off; off >>= 1) {
            float osv = __shfl_xor(sv, off, 64);
            int   okk = __shfl_xor(kk, off, 64);
            if (osv < sv || (osv == sv && okk < kk)) { sv = osv; kk = okk; }
        }
        if (l == 0) {
            unsigned ue = __float_as_uint(sv);
            ue = (ue >> 31) ? ~ue : (ue | 0x80000000u);
            key_s[m] = ((unsigned long long)ue << 32) | (unsigned)kk;
        }
    }
    __syncthreads();
    if (tid < 64 && (c_s[tid] > 0 || ovf_s[tid]))
        out[IDX_OFF + n0 + tid] = (float)(unsigned)(key_s[tid] & 0xFFFFFFFFULL);
}

// ---------------------------------------------------------------------------
// K3: gather z_q via LDS-staged codebook rows, straight-through write
// out = fl(z + fl(z_q - z)), loss partials + fused final scale via ticket.
// (Arithmetic order untouched — bit-exact vs previous passing version.)
__global__ __launch_bounds__(256) void k_gather(const float* __restrict__ z,
                                                const float* __restrict__ cb,
                                                float* __restrict__ out,
                                                float* __restrict__ ws) {
    __shared__ float s_cb[64][65];
    __shared__ int   s_idx[64];
    __shared__ float s_red[4];
    const int tid = threadIdx.x;
    const int b  = blockIdx.x >> 4;
    const int p0 = (blockIdx.x & 15) * 64;

    if (tid < 64)
        s_idx[tid] = (int)out[IDX_OFF + (size_t)b * HW + p0 + tid];
    __syncthreads();

    const int p    = tid & 63;
    const int cgrp = tid >> 6;
    const int row  = tid >> 2;
    const int q4   = tid & 3;
    const float* zrow = z   + (size_t)b * EMB_DIM * HW + p0 + p;
    float*       orow = out + (size_t)b * EMB_DIM * HW + p0 + p;

    float acc = 0.0f;
#pragma unroll 1
    for (int d0 = 0; d0 < EMB_DIM; d0 += 64) {
        const float* cr = cb + (size_t)s_idx[row] * EMB_DIM + d0;
#pragma unroll
        for (int pass = 0; pass < 4; ++pass) {
            int c = q4 * 4 + pass * 16;
            *(float4*)(&s_cb[row][c]) = *(const float4*)(cr + c);
        }
        __syncthreads();
#pragma unroll
        for (int j = 0; j < 16; ++j) {
            int c = cgrp * 16 + j;
            float zq = s_cb[p][c];
            float zv = zrow[(size_t)(d0 + c) * HW];
            float d  = zq - zv;
            orow[(size_t)(d0 + c) * HW] = zv + d;
            acc += d * d;
        }
        __syncthreads();
    }
#pragma unroll
    for (int off = 32; off > 0; off >>= 1) acc += __shfl_down(acc, off, 64);
    if ((tid & 63) == 0) s_red[tid >> 6] = acc;
    __syncthreads();
    if (tid == 0) {
        atomicAdd(ws, s_red[0] + s_red[1] + s_red[2] + s_red[3]);
        __threadfence();
        unsigned old = atomicAdd((unsigned int*)ws + 1, 1u);
        if (old == 511u) {
            float total = atomicAdd(ws, 0.0f);
            out[LOSS_OFF] = 1.25f * (total * (1.0f / 8388608.0f));
        }
    }
}

// ---------------------------------------------------------------------------
extern "C" void kernel_launch(void* const* d_in, const int* in_sizes, int n_in,
                              void* d_out, int out_size, void* d_ws, size_t ws_size,
                              hipStream_t stream) {
    const float* z  = (const float*)d_in[0];
    const float* cb = (const float*)d_in[1];
    float* out = (float*)d_out;
    float* ws  = (float*)d_ws;

    k_prep   <<<260, 256, 0, stream>>>(z, cb, ws, out);
    k_filter <<<512, 256, 0, stream>>>(ws, out);
    k_rescore<<<512, 256, 0, stream>>>(z, cb, ws, out);
    k_gather <<<512, 256, 0, stream>>>(z, cb, out, ws);
}

// Round 4
// 181.177 us; speedup vs baseline: 1.5030x; 1.0306x over previous
//
#include <hip/hip_runtime.h>

// Problem constants
#define NUM_EMB 1024
#define EMB_DIM 256
#define BATCH   32
#define HW      1024
#define Z_ELEMS (BATCH*EMB_DIM*HW)   // 8388608
#define LOSS_OFF Z_ELEMS
#define IDX_OFF (Z_ELEMS+1)

// ---------------------------------------------------------------------------
// Workspace layout (ws is 256 MiB, poisoned by harness between iterations —
// everything here is recomputed every launch; nothing persists).
//   float[0]  loss accumulator     float[1](as uint) ticket
//   floats [16    .. 1040)   cnorm[1024]
//   floats [2048  .. 34816)  znorm[32768]       (exact pairwise tree)
//   floats [36864 .. 69632)  s1z[32768] = sum_d |z_d|
//   ints   [69632 .. 102400) cand_cnt[32768]  (0 resolved, 1025 overflow)
//   ints   [102400..1150976) cand_idx[32768][32] compacted survivors
//   halves [2359296..2621440)  Bt — codebook*1024 fp16, MFMA-B-frag tiled (512 KB)
//   halves [4194304..12582912) z16 — z fp16, MFMA-A-frag tiled (16 MB)
// out is ONLY written as final output (z_q region, loss, indices).
#define WS_CNORM_OFF 16
#define WS_ZNORM_OFF 2048
#define WS_S1Z_OFF   36864
#define WS_CNT_IOFF  69632
#define WS_CAND_IOFF 102400
#define WS_BT_HOFF   2359296
#define WS_Z16_HOFF  4194304
#define CAND_CAP  32

// Per-query filter threshold: T = T_SLOPE*S1z + T_BIAS (proof in round-1 notes:
// fp16 single pass, codebook scaled x1024 => need 3.82e-6*S1z + 1e-4; chosen
// slope/bias give 1.57x / 3x margin). Unchanged from the passing version.
#define T_SLOPE 6.0e-6f
#define T_BIAS  3.0e-4f

typedef __attribute__((ext_vector_type(8))) _Float16 f16x8;
typedef __attribute__((ext_vector_type(4))) float f32x4;

// ---------------------------------------------------------------------------
// K0: fused prep, 388 blocks.
//  blk 0..3     cnorm[k] exact pairwise tree
//  blk 4..259   znorm/S1z/z16: 128 queries per block, 2 threads per query
//               (one per 128-d half — the exact tree's natural seam; halves
//               and the final fadd are bit-identical to the 1-thread version)
//  blk 260..387 pack codebook*1024 -> fp16 Bt in MFMA B-fragment order
__global__ __launch_bounds__(256) void k_prep(const float* __restrict__ z,
                                              const float* __restrict__ cb,
                                              float* __restrict__ ws) {
    __shared__ float h_lds[128];
    __shared__ float s1_lds[128];
    const int tid = threadIdx.x;
    const int blk = blockIdx.x;
    if (blk == 0 && tid == 0) { ws[0] = 0.0f; ((unsigned*)ws)[1] = 0u; }
    if (blk < 4) {
        int k = blk * 256 + tid;
        const float* row = cb + (size_t)k * EMB_DIM;
        float hsum[2];
#pragma unroll
        for (int h = 0; h < 2; ++h) {
            const float* a = row + h * 128;
            float r[8];
#pragma unroll
            for (int j = 0; j < 8; ++j) r[j] = __fmul_rn(a[j], a[j]);
            for (int i = 8; i < 128; i += 8)
#pragma unroll
                for (int j = 0; j < 8; ++j)
                    r[j] = __fadd_rn(r[j], __fmul_rn(a[i + j], a[i + j]));
            hsum[h] = __fadd_rn(__fadd_rn(__fadd_rn(r[0], r[1]), __fadd_rn(r[2], r[3])),
                                __fadd_rn(__fadd_rn(r[4], r[5]), __fadd_rn(r[6], r[7])));
        }
        ws[WS_CNORM_OFF + k] = __fadd_rn(hsum[0], hsum[1]);
    } else if (blk < 260) {
        const int q = tid & 127, h = tid >> 7;      // 2 threads per query
        const int n = (blk - 4) * 128 + q;
        const int b = n >> 10, p = n & 1023;
        const float* base = z + (size_t)b * EMB_DIM * HW + p;
        _Float16* z16 = (_Float16*)ws + WS_Z16_HOFF;
        const int qb = n >> 6, r0 = n & 63;
        const int mt = r0 >> 4, l0 = r0 & 15;
        const size_t tb = (size_t)qb * 2048;        // f16x8 slots per query-block
        float racc[8], v[8];
        float s1 = 0.0f;
#pragma unroll
        for (int j = 0; j < 8; ++j) v[j] = base[(size_t)(h * 128 + j) * HW];
        {
            int d0 = h * 128;
            int c = d0 >> 5, kh = (d0 >> 3) & 3;
            f16x8 g;
#pragma unroll
            for (int j = 0; j < 8; ++j) g[j] = (_Float16)v[j];
            *(f16x8*)(z16 + (tb + (size_t)(c * 4 + mt) * 64 + kh * 16 + l0) * 8) = g;
        }
#pragma unroll
        for (int j = 0; j < 8; ++j) { racc[j] = __fmul_rn(v[j], v[j]); s1 += fabsf(v[j]); }
        for (int i = 8; i < 128; i += 8) {
#pragma unroll
            for (int j = 0; j < 8; ++j) v[j] = base[(size_t)(h * 128 + i + j) * HW];
            int d0 = h * 128 + i;
            int c = d0 >> 5, kh = (d0 >> 3) & 3;
            f16x8 g;
#pragma unroll
            for (int j = 0; j < 8; ++j) g[j] = (_Float16)v[j];
            *(f16x8*)(z16 + (tb + (size_t)(c * 4 + mt) * 64 + kh * 16 + l0) * 8) = g;
#pragma unroll
            for (int j = 0; j < 8; ++j) {
                racc[j] = __fadd_rn(racc[j], __fmul_rn(v[j], v[j]));
                s1 += fabsf(v[j]);
            }
        }
        float half = __fadd_rn(__fadd_rn(__fadd_rn(racc[0], racc[1]), __fadd_rn(racc[2], racc[3])),
                               __fadd_rn(__fadd_rn(racc[4], racc[5]), __fadd_rn(racc[6], racc[7])));
        if (h == 1) { h_lds[q] = half; s1_lds[q] = s1; }
        __syncthreads();
        if (h == 0) {
            ws[WS_ZNORM_OFF + n] = __fadd_rn(half, h_lds[q]);   // exact: fadd(half0, half1)
            ws[WS_S1Z_OFF + n] = s1 + s1_lds[q];                // bound input only
        }
    } else {
        unsigned u = (unsigned)(blk - 260) * 256 + tid;   // 0..32767
        int lane = u & 63;
        int nt   = (u >> 6) & 15;
        int cc   = (u >> 10) & 7;
        int s    = (u >> 13) & 3;
        int code = s * 256 + nt * 16 + (lane & 15);
        int d0   = cc * 32 + (lane >> 4) * 8;
        const float* cr = cb + (size_t)code * EMB_DIM + d0;
        f16x8 v;
#pragma unroll
        for (int j = 0; j < 8; ++j) v[j] = (_Float16)(cr[j] * 1024.0f);
        _Float16* Bt = (_Float16*)ws + WS_BT_HOFF;
        *(f16x8*)(Bt + ((((size_t)(s * 8 + cc) * 16 + nt) * 64 + lane) * 8)) = v;
    }
}

// ---------------------------------------------------------------------------
// K1: MFMA candidate filter, all 4 slabs per block. (structure unchanged from
// the passing round-2 version; only scratch pointers moved from out to ws)
__global__ __launch_bounds__(256, 3) void k_filter(float* __restrict__ ws,
                                                   float* __restrict__ out) {
    __shared__ __attribute__((aligned(16))) _Float16 A_lds[2048 * 8];  // 32 KB
    __shared__ float wm[256];
    __shared__ float rmin_s[64];
    __shared__ float tq_s[64];
    __shared__ float thr_s[64];
    __shared__ int   cnt_s[64];
    __shared__ int   bidx_s[64][CAND_CAP];   // 8 KB
    __shared__ float bval_s[64][CAND_CAP];   // 8 KB

    const int tid = threadIdx.x;
    const int w = tid >> 6, l = tid & 63;
    const int qb = blockIdx.x, nq0 = qb * 64;

    const f16x8* B8 = (const f16x8*)((const _Float16*)ws + WS_BT_HOFF);
    const f16x8* Ag = (const f16x8*)((const _Float16*)ws + WS_Z16_HOFF) + (size_t)qb * 2048;
    f16x8* Al = (f16x8*)A_lds;

    // prologue: issue B loads for steps 0,1 before A staging so they overlap
    f16x8 b[3][4];
#pragma unroll
    for (int t = 0; t < 2; ++t)
#pragma unroll
        for (int nt = 0; nt < 4; ++nt)
            b[t][nt] = B8[((size_t)(t * 16) + w * 4 + nt) * 64 + l];
    // stage A tile (linear copy, one barrier, no per-chunk barriers after)
#pragma unroll
    for (int i = 0; i < 8; ++i) Al[i * 256 + tid] = Ag[i * 256 + tid];
    if (tid < 64) {
        cnt_s[tid] = 0;
        rmin_s[tid] = 3.4e38f;
        tq_s[tid] = fmaf(T_SLOPE, ws[WS_S1Z_OFF + nq0 + tid], T_BIAS);
    }
    __syncthreads();

    const float* cn = ws + WS_CNORM_OFF;
    f32x4 acc[4][4];
#pragma unroll
    for (int mt = 0; mt < 4; ++mt)
#pragma unroll
        for (int nt = 0; nt < 4; ++nt) acc[mt][nt] = (f32x4)(0.0f);

#pragma unroll
    for (int t = 0; t < 32; ++t) {           // t = slab*8 + chunk
        const int c = t & 7, s = t >> 3;
        if (t + 2 < 32) {                    // depth-2 B prefetch
            const int t2 = t + 2;
#pragma unroll
            for (int nt = 0; nt < 4; ++nt)
                b[t2 % 3][nt] = B8[((size_t)(t2 * 16) + w * 4 + nt) * 64 + l];
        }
#pragma unroll
        for (int mt = 0; mt < 4; ++mt) {
            f16x8 av = Al[(c * 4 + mt) * 64 + l];
#pragma unroll
            for (int nt = 0; nt < 4; ++nt)
                acc[mt][nt] = __builtin_amdgcn_mfma_f32_16x16x32_f16(av, b[t % 3][nt], acc[mt][nt], 0, 0, 0);
        }
        if (c == 7) {
            // ---- slab epilogue (B loads for next slab already in flight) ----
            float c2[4];
#pragma unroll
            for (int nt = 0; nt < 4; ++nt)
                c2[nt] = cn[s * 256 + (w * 4 + nt) * 16 + (l & 15)];
            float vmin[4][4];
#pragma unroll
            for (int mt = 0; mt < 4; ++mt)
#pragma unroll
                for (int reg = 0; reg < 4; ++reg) vmin[mt][reg] = 3.4e38f;
#pragma unroll
            for (int mt = 0; mt < 4; ++mt)
#pragma unroll
                for (int nt = 0; nt < 4; ++nt)
#pragma unroll
                    for (int reg = 0; reg < 4; ++reg) {
                        float sv = fmaf(-0.001953125f, acc[mt][nt][reg], c2[nt]);  // -2/1024
                        acc[mt][nt][reg] = sv;
                        vmin[mt][reg] = fminf(vmin[mt][reg], sv);
                    }
#pragma unroll
            for (int msk = 1; msk < 16; msk <<= 1)
#pragma unroll
                for (int mt = 0; mt < 4; ++mt)
#pragma unroll
                    for (int reg = 0; reg < 4; ++reg)
                        vmin[mt][reg] = fminf(vmin[mt][reg], __shfl_xor(vmin[mt][reg], msk, 64));
            if ((l & 15) == 0) {
#pragma unroll
                for (int mt = 0; mt < 4; ++mt)
#pragma unroll
                    for (int reg = 0; reg < 4; ++reg)
                        wm[w * 64 + mt * 16 + (l >> 4) * 4 + reg] = vmin[mt][reg];
            }
            __syncthreads();
            if (tid < 64) {
                float smin = fminf(fminf(wm[tid], wm[64 + tid]),
                                   fminf(wm[128 + tid], wm[192 + tid]));
                float rm = fminf(rmin_s[tid], smin);
                rmin_s[tid] = rm;
                thr_s[tid] = rm + tq_s[tid];
            }
            __syncthreads();
            // append candidates under running threshold
#pragma unroll
            for (int mt = 0; mt < 4; ++mt)
#pragma unroll
                for (int reg = 0; reg < 4; ++reg) {
                    int m = mt * 16 + (l >> 4) * 4 + reg;
                    float th = thr_s[m];
#pragma unroll
                    for (int nt = 0; nt < 4; ++nt) {
                        float sv = acc[mt][nt][reg];
                        if (sv <= th) {
                            int kg = s * 256 + (w * 4 + nt) * 16 + (l & 15);
                            int pos = atomicAdd(&cnt_s[m], 1);
                            if (pos < CAND_CAP) { bidx_s[m][pos] = kg; bval_s[m][pos] = sv; }
                        }
                    }
                }
            // re-zero accumulators for next slab
#pragma unroll
            for (int mt = 0; mt < 4; ++mt)
#pragma unroll
                for (int nt = 0; nt < 4; ++nt) acc[mt][nt] = (f32x4)(0.0f);
        }
    }
    __syncthreads();   // all appends visible
    if (tid < 64) {
        int n = nq0 + tid;
        int c = cnt_s[tid];
        int* cnt_g  = (int*)ws + WS_CNT_IOFF;
        int* cand_g = (int*)ws + WS_CAND_IOFF;
        if (c > CAND_CAP) {
            cnt_g[n] = 1025;                  // overflow sentinel -> full rescan
        } else {
            float th = thr_s[tid];            // global min + T (after slab 3)
            int m = 0, keep = 0;
            for (int j = 0; j < c; ++j) {
                if (bval_s[tid][j] <= th) {
                    cand_g[(size_t)n * CAND_CAP + m] = bidx_s[tid][j];
                    if (m == 0) keep = bidx_s[tid][j];
                    ++m;
                }
            }
            if (m == 1) {
                out[IDX_OFF + n] = (float)keep;   // resolved here
                cnt_g[n] = 0;
            } else {
                cnt_g[n] = m;
            }
        }
    }
}

// ---------------------------------------------------------------------------
// K2: fused exact rescore + gather + loss. Block = 64 consecutive queries.
//  - z tile [256 d][64 q] fp32 staged coalesced ONCE (exact bits) — shared by
//    rescore (dot source) and gather (zv source), halving z HBM traffic.
//  - rescore: candidate-per-thread, bit-proven recipe (serial ascending-d fma
//    dot, fold fl(fl(z2+c2)-fl(2*dot))); per-query argmin via order-preserving
//    (enc(sv)<<32|k) atomicMin == min sv then smallest k == reference ties.
//  - gather: cb rows staged to LDS exactly as the previous passing k_gather;
//    zv read from z_lds (same bits as the global re-read it replaces);
//    per-thread accumulation order identical; ticket finalizes loss (512 blks).
__global__ __launch_bounds__(256) void k_resgather(const float* __restrict__ z,
                                                   const float* __restrict__ cb,
                                                   float* __restrict__ ws,
                                                   float* __restrict__ out) {
    __shared__ __attribute__((aligned(16))) float z_lds[256][64];   // 64 KB
    __shared__ float s_cb[64][65];                                  // 16.6 KB
    __shared__ int   idx_s[64];
    __shared__ int   c_s[64];
    __shared__ int   offI[64];
    __shared__ int   ovf_s[64];
    __shared__ unsigned long long key_s[64];
    __shared__ float s_red[4];

    const int tid = threadIdx.x;
    const int w = tid >> 6, l = tid & 63;
    const int n0 = blockIdx.x * 64;
    const int b = n0 >> 10, p0 = n0 & 1023;
    const int* cnt  = (const int*)ws + WS_CNT_IOFF;
    const int* cand = (const int*)ws + WS_CAND_IOFF;
    const float* cn = ws + WS_CNORM_OFF;

    if (tid < 64) {
        int c = cnt[n0 + tid];
        int ov = (c > CAND_CAP) ? 1 : 0;
        ovf_s[tid] = ov;
        int cc = (ov || c < 2) ? 0 : c;
        c_s[tid] = cc;
        key_s[tid] = ~0ULL;
        if (cc == 0 && !ov) idx_s[tid] = (int)out[IDX_OFF + n0 + tid];  // filter-resolved
        int v = cc;
#pragma unroll
        for (int off = 1; off < 64; off <<= 1) {
            int u = __shfl_up(v, off, 64);
            if (l >= off) v += u;
        }
        offI[tid] = v;
    }
    __syncthreads();

    // stage z tile: [d][q] fp32, float4 coalesced (exact bits); always needed
    {
        const float* zb = z + (size_t)b * EMB_DIM * HW + p0;
        const int q4 = tid & 15, g = tid >> 4;
#pragma unroll 4
        for (int r = 0; r < 16; ++r) {
            int d = r * 16 + g;
            float4 vv = *(const float4*)(zb + (size_t)d * HW + q4 * 4);
            *(float4*)&z_lds[d][q4 * 4] = vv;
        }
    }
    __syncthreads();

    // candidate-per-thread exact rescore
    const int C = offI[63];
    for (int t = tid; t < C; t += 256) {
        int lo = 0, hi = 63;
        while (lo < hi) { int mid = (lo + hi) >> 1; if (offI[mid] > t) hi = mid; else lo = mid + 1; }
        const int m = lo;
        const int j = t - (m ? offI[m - 1] : 0);
        const int n = n0 + m;
        const int kk = cand[(size_t)n * CAND_CAP + j];
        const float* r = cb + (size_t)kk * EMB_DIM;
        float dot = 0.0f;
#pragma unroll 8
        for (int d = 0; d < EMB_DIM; ++d)
            dot = fmaf(z_lds[d][m], r[d], dot);
        float t1 = __fadd_rn(ws[WS_ZNORM_OFF + n], cn[kk]);
        float sv = __fadd_rn(t1, __fmul_rn(-2.0f, dot));
        unsigned ue = __float_as_uint(sv);
        ue = (ue >> 31) ? ~ue : (ue | 0x80000000u);
        atomicMin(&key_s[m], ((unsigned long long)ue << 32) | (unsigned)kk);
    }

    // overflow queries (rare): distributed exact full scan, wave per query
    for (int m = w; m < 64; m += 4) {
        if (!ovf_s[m]) continue;
        const int n = n0 + m;
        const float z2 = ws[WS_ZNORM_OFF + n];
        float sv = 3.4e38f; int kk = NUM_EMB;
        for (int k0 = l; k0 < NUM_EMB; k0 += 64) {
            const float* r = cb + (size_t)k0 * EMB_DIM;
            float dot = 0.0f;
#pragma unroll 8
            for (int d = 0; d < EMB_DIM; ++d)
                dot = fmaf(z_lds[d][m], r[d], dot);
            float t1 = __fadd_rn(z2, cn[k0]);
            float s2 = __fadd_rn(t1, __fmul_rn(-2.0f, dot));
            if (s2 < sv) { sv = s2; kk = k0; }   // ascending k: < keeps first
        }
#pragma unroll
        for (int off = 32; off; off >>= 1) {
            float osv = __shfl_xor(sv, off, 64);
            int   okk = __shfl_xor(kk, off, 64);
            if (osv < sv || (osv == sv && okk < kk)) { sv = osv; kk = okk; }
        }
        if (l == 0) {
            unsigned ue = __float_as_uint(sv);
            ue = (ue >> 31) ? ~ue : (ue | 0x80000000u);
            key_s[m] = ((unsigned long long)ue << 32) | (unsigned)kk;
        }
    }
    __syncthreads();
    if (tid < 64 && (c_s[tid] > 0 || ovf_s[tid])) {
        int kk = (int)(unsigned)(key_s[tid] & 0xFFFFFFFFULL);
        idx_s[tid] = kk;
        out[IDX_OFF + n0 + tid] = (float)kk;
    }
    __syncthreads();

    // ---- gather phase (identical arithmetic/order to the old k_gather,
    //      zv sourced from z_lds instead of a global re-read) ----
    const int p    = tid & 63;
    const int cgrp = tid >> 6;
    const int row  = tid >> 2;
    const int q4   = tid & 3;
    float* orow = out + (size_t)b * EMB_DIM * HW + p0 + p;

    float acc = 0.0f;
#pragma unroll 1
    for (int d0 = 0; d0 < EMB_DIM; d0 += 64) {
        const float* cr = cb + (size_t)idx_s[row] * EMB_DIM + d0;
#pragma unroll
        for (int pass = 0; pass < 4; ++pass) {
            int c = q4 * 4 + pass * 16;
            *(float4*)(&s_cb[row][c]) = *(const float4*)(cr + c);
        }
        __syncthreads();
#pragma unroll
        for (int j = 0; j < 16; ++j) {
            int c = cgrp * 16 + j;
            float zq = s_cb[p][c];
            float zv = z_lds[d0 + c][p];
            float d  = zq - zv;
            orow[(size_t)(d0 + c) * HW] = zv + d;
            acc += d * d;
        }
        __syncthreads();
    }
#pragma unroll
    for (int off = 32; off > 0; off >>= 1) acc += __shfl_down(acc, off, 64);
    if ((tid & 63) == 0) s_red[tid >> 6] = acc;
    __syncthreads();
    if (tid == 0) {
        atomicAdd(ws, s_red[0] + s_red[1] + s_red[2] + s_red[3]);
        __threadfence();
        unsigned old = atomicAdd((unsigned int*)ws + 1, 1u);
        if (old == 511u) {
            float total = atomicAdd(ws, 0.0f);
            out[LOSS_OFF] = 1.25f * (total * (1.0f / 8388608.0f));
        }
    }
}

// ---------------------------------------------------------------------------
extern "C" void kernel_launch(void* const* d_in, const int* in_sizes, int n_in,
                              void* d_out, int out_size, void* d_ws, size_t ws_size,
                              hipStream_t stream) {
    const float* z  = (const float*)d_in[0];
    const float* cb = (const float*)d_in[1];
    float* out = (float*)d_out;
    float* ws  = (float*)d_ws;

    k_prep     <<<388, 256, 0, stream>>>(z, cb, ws);
    k_filter   <<<512, 256, 0, stream>>>(ws, out);
    k_resgather<<<512, 256, 0, stream>>>(z, cb, ws, out);
}

// Round 5
// 167.618 us; speedup vs baseline: 1.6245x; 1.0809x over previous
//
#include <hip/hip_runtime.h>

// Problem constants
#define NUM_EMB 1024
#define EMB_DIM 256
#define BATCH   32
#define HW      1024
#define Z_ELEMS (BATCH*EMB_DIM*HW)   // 8388608
#define LOSS_OFF Z_ELEMS
#define IDX_OFF (Z_ELEMS+1)

// ---------------------------------------------------------------------------
// Workspace layout (ws is 256 MiB, poisoned between iterations).
//   float[0]  loss accumulator     float[1](as uint) ticket
//   floats [16    .. 1040)   cnorm[1024]
//   ints   [69632 .. 102400) cand_cnt[32768]  (0 resolved, 1025 overflow)
//   ints   [102400..1150976) cand_idx[32768][32] compacted survivors
//   halves [2359296..2621440) Bt — codebook*1024 fp16, MFMA-B-frag tiled (512 KB)
// z16 / znorm / s1z scratch GONE: A staged from fp32 z in k_filter (s1z
// computed there); znorm computed in k_resgather from its exact z_lds tile.
#define WS_CNORM_OFF 16
#define WS_CNT_IOFF  69632
#define WS_CAND_IOFF 102400
#define WS_BT_HOFF   2359296
#define CAND_CAP  32

// Per-query filter threshold: T = T_SLOPE*S1z + T_BIAS (proof in round-1 notes:
// fp16 single pass, codebook scaled x1024 => need 3.82e-6*S1z + 1e-4; chosen
// slope/bias give 1.57x / 3x margin; s1z is a bound input only, so fp32
// accumulation order is free).
#define T_SLOPE 6.0e-6f
#define T_BIAS  3.0e-4f

typedef __attribute__((ext_vector_type(8))) _Float16 f16x8;
typedef __attribute__((ext_vector_type(4))) float f32x4;

// ---------------------------------------------------------------------------
// K0: tiny prep, 132 blocks: cnorm (exact pairwise tree) + Bt fp16 pack.
__global__ __launch_bounds__(256) void k_prep(const float* __restrict__ cb,
                                              float* __restrict__ ws) {
    const int tid = threadIdx.x;
    const int blk = blockIdx.x;
    if (blk == 0 && tid == 0) { ws[0] = 0.0f; ((unsigned*)ws)[1] = 0u; }
    if (blk < 4) {
        int k = blk * 256 + tid;
        const float* row = cb + (size_t)k * EMB_DIM;
        float hsum[2];
#pragma unroll
        for (int h = 0; h < 2; ++h) {
            const float* a = row + h * 128;
            float r[8];
#pragma unroll
            for (int j = 0; j < 8; ++j) r[j] = __fmul_rn(a[j], a[j]);
            for (int i = 8; i < 128; i += 8)
#pragma unroll
                for (int j = 0; j < 8; ++j)
                    r[j] = __fadd_rn(r[j], __fmul_rn(a[i + j], a[i + j]));
            hsum[h] = __fadd_rn(__fadd_rn(__fadd_rn(r[0], r[1]), __fadd_rn(r[2], r[3])),
                                __fadd_rn(__fadd_rn(r[4], r[5]), __fadd_rn(r[6], r[7])));
        }
        ws[WS_CNORM_OFF + k] = __fadd_rn(hsum[0], hsum[1]);
    } else {
        unsigned u = (unsigned)(blk - 4) * 256 + tid;   // 0..32767
        int lane = u & 63;
        int nt   = (u >> 6) & 15;
        int cc   = (u >> 10) & 7;
        int s    = (u >> 13) & 3;
        int code = s * 256 + nt * 16 + (lane & 15);
        int d0   = cc * 32 + (lane >> 4) * 8;
        const float* cr = cb + (size_t)code * EMB_DIM + d0;
        f16x8 v;
#pragma unroll
        for (int j = 0; j < 8; ++j) v[j] = (_Float16)(cr[j] * 1024.0f);
        _Float16* Bt = (_Float16*)ws + WS_BT_HOFF;
        *(f16x8*)(Bt + ((((size_t)(s * 8 + cc) * 16 + nt) * 64 + lane) * 8)) = v;
    }
}

// ---------------------------------------------------------------------------
// K1: MFMA candidate filter, all 4 slabs per block.
// A tile now staged DIRECTLY from fp32 z: wave w covers d in [64w,64w+64),
// lane l owns query l; scalar loads coalesce 256B/wave-instr; RNE fp16
// conversion identical to the old prep pack; LDS writes are the same fragment
// layout (256B-contiguous per 16-lane group). s1z accumulated during staging
// (|v| in load order, 4-way combine) — bound input only. Rest unchanged from
// the passing round-2 structure.
__global__ __launch_bounds__(256, 3) void k_filter(const float* __restrict__ z,
                                                   float* __restrict__ ws,
                                                   float* __restrict__ out) {
    __shared__ __attribute__((aligned(16))) _Float16 A_lds[2048 * 8];  // 32 KB
    __shared__ float wm[256];
    __shared__ float rmin_s[64];
    __shared__ float tq_s[64];
    __shared__ float thr_s[64];
    __shared__ int   cnt_s[64];
    __shared__ int   bidx_s[64][CAND_CAP];   // 8 KB
    __shared__ float bval_s[64][CAND_CAP];   // 8 KB

    const int tid = threadIdx.x;
    const int w = tid >> 6, l = tid & 63;
    const int qb = blockIdx.x, nq0 = qb * 64;
    const int bb = nq0 >> 10, p0 = nq0 & 1023;

    const f16x8* B8 = (const f16x8*)((const _Float16*)ws + WS_BT_HOFF);
    f16x8* Al = (f16x8*)A_lds;

    // prologue: issue B loads for steps 0,1 so they fly under A staging
    f16x8 b[3][4];
#pragma unroll
    for (int t = 0; t < 2; ++t)
#pragma unroll
        for (int nt = 0; nt < 4; ++nt)
            b[t][nt] = B8[((size_t)(t * 16) + w * 4 + nt) * 64 + l];

    // stage A from fp32 z + s1 partial
    {
        const float* zq = z + (size_t)bb * EMB_DIM * HW + p0 + l;
        float s1p = 0.0f;
#pragma unroll
        for (int i8 = 0; i8 < 8; ++i8) {
            const int d0 = w * 64 + i8 * 8;
            float v[8];
#pragma unroll
            for (int j = 0; j < 8; ++j) v[j] = zq[(size_t)(d0 + j) * HW];
            f16x8 g;
#pragma unroll
            for (int j = 0; j < 8; ++j) { g[j] = (_Float16)v[j]; s1p += fabsf(v[j]); }
            const int c = d0 >> 5, kh = (d0 >> 3) & 3;
            Al[(c * 4 + (l >> 4)) * 64 + kh * 16 + (l & 15)] = g;
        }
        wm[tid] = s1p;
    }
    if (tid < 64) { cnt_s[tid] = 0; rmin_s[tid] = 3.4e38f; }
    __syncthreads();
    if (tid < 64)
        tq_s[tid] = fmaf(T_SLOPE,
                         __fadd_rn(__fadd_rn(wm[tid], wm[64 + tid]),
                                   __fadd_rn(wm[128 + tid], wm[192 + tid])),
                         T_BIAS);
    __syncthreads();

    const float* cn = ws + WS_CNORM_OFF;
    f32x4 acc[4][4];
#pragma unroll
    for (int mt = 0; mt < 4; ++mt)
#pragma unroll
        for (int nt = 0; nt < 4; ++nt) acc[mt][nt] = (f32x4)(0.0f);

#pragma unroll
    for (int t = 0; t < 32; ++t) {           // t = slab*8 + chunk
        const int c = t & 7, s = t >> 3;
        if (t + 2 < 32) {                    // depth-2 B prefetch
            const int t2 = t + 2;
#pragma unroll
            for (int nt = 0; nt < 4; ++nt)
                b[t2 % 3][nt] = B8[((size_t)(t2 * 16) + w * 4 + nt) * 64 + l];
        }
#pragma unroll
        for (int mt = 0; mt < 4; ++mt) {
            f16x8 av = Al[(c * 4 + mt) * 64 + l];
#pragma unroll
            for (int nt = 0; nt < 4; ++nt)
                acc[mt][nt] = __builtin_amdgcn_mfma_f32_16x16x32_f16(av, b[t % 3][nt], acc[mt][nt], 0, 0, 0);
        }
        if (c == 7) {
            // ---- slab epilogue (B loads for next slab already in flight) ----
            float c2[4];
#pragma unroll
            for (int nt = 0; nt < 4; ++nt)
                c2[nt] = cn[s * 256 + (w * 4 + nt) * 16 + (l & 15)];
            float vmin[4][4];
#pragma unroll
            for (int mt = 0; mt < 4; ++mt)
#pragma unroll
                for (int reg = 0; reg < 4; ++reg) vmin[mt][reg] = 3.4e38f;
#pragma unroll
            for (int mt = 0; mt < 4; ++mt)
#pragma unroll
                for (int nt = 0; nt < 4; ++nt)
#pragma unroll
                    for (int reg = 0; reg < 4; ++reg) {
                        float sv = fmaf(-0.001953125f, acc[mt][nt][reg], c2[nt]);  // -2/1024
                        acc[mt][nt][reg] = sv;
                        vmin[mt][reg] = fminf(vmin[mt][reg], sv);
                    }
#pragma unroll
            for (int msk = 1; msk < 16; msk <<= 1)
#pragma unroll
                for (int mt = 0; mt < 4; ++mt)
#pragma unroll
                    for (int reg = 0; reg < 4; ++reg)
                        vmin[mt][reg] = fminf(vmin[mt][reg], __shfl_xor(vmin[mt][reg], msk, 64));
            if ((l & 15) == 0) {
#pragma unroll
                for (int mt = 0; mt < 4; ++mt)
#pragma unroll
                    for (int reg = 0; reg < 4; ++reg)
                        wm[w * 64 + mt * 16 + (l >> 4) * 4 + reg] = vmin[mt][reg];
            }
            __syncthreads();
            if (tid < 64) {
                float smin = fminf(fminf(wm[tid], wm[64 + tid]),
                                   fminf(wm[128 + tid], wm[192 + tid]));
                float rm = fminf(rmin_s[tid], smin);
                rmin_s[tid] = rm;
                thr_s[tid] = rm + tq_s[tid];
            }
            __syncthreads();
            // append candidates under running threshold
#pragma unroll
            for (int mt = 0; mt < 4; ++mt)
#pragma unroll
                for (int reg = 0; reg < 4; ++reg) {
                    int m = mt * 16 + (l >> 4) * 4 + reg;
                    float th = thr_s[m];
#pragma unroll
                    for (int nt = 0; nt < 4; ++nt) {
                        float sv = acc[mt][nt][reg];
                        if (sv <= th) {
                            int kg = s * 256 + (w * 4 + nt) * 16 + (l & 15);
                            int pos = atomicAdd(&cnt_s[m], 1);
                            if (pos < CAND_CAP) { bidx_s[m][pos] = kg; bval_s[m][pos] = sv; }
                        }
                    }
                }
            // re-zero accumulators for next slab
#pragma unroll
            for (int mt = 0; mt < 4; ++mt)
#pragma unroll
                for (int nt = 0; nt < 4; ++nt) acc[mt][nt] = (f32x4)(0.0f);
        }
    }
    __syncthreads();   // all appends visible
    if (tid < 64) {
        int n = nq0 + tid;
        int c = cnt_s[tid];
        int* cnt_g  = (int*)ws + WS_CNT_IOFF;
        int* cand_g = (int*)ws + WS_CAND_IOFF;
        if (c > CAND_CAP) {
            cnt_g[n] = 1025;                  // overflow sentinel -> full rescan
        } else {
            float th = thr_s[tid];            // global min + T (after slab 3)
            int m = 0, keep = 0;
            for (int j = 0; j < c; ++j) {
                if (bval_s[tid][j] <= th) {
                    cand_g[(size_t)n * CAND_CAP + m] = bidx_s[tid][j];
                    if (m == 0) keep = bidx_s[tid][j];
                    ++m;
                }
            }
            if (m == 1) {
                out[IDX_OFF + n] = (float)keep;   // resolved here
                cnt_g[n] = 0;
            } else {
                cnt_g[n] = m;
            }
        }
    }
}

// ---------------------------------------------------------------------------
// K2: fused exact znorm + rescore + gather + loss. Block = 64 queries.
// LDS cut to ~74 KB (2 blocks/CU): s_cb replaced by a [64][33] half-panel
// staged twice per d0, with the per-thread gather d-sequence (and loss
// partial order) bit-preserved. znorm computed here from the exact fp32
// z_lds via the bit-identical pairwise tree (2 threads/query, 128-d seam),
// skipped when the block has no unresolved queries.
__global__ __launch_bounds__(256) void k_resgather(const float* __restrict__ z,
                                                   const float* __restrict__ cb,
                                                   float* __restrict__ ws,
                                                   float* __restrict__ out) {
    __shared__ __attribute__((aligned(16))) float z_lds[256][64];   // 64 KB
    __shared__ float s_half[64][33];                                // 8.4 KB
    __shared__ int   idx_s[64];
    __shared__ int   c_s[64];
    __shared__ int   offI[64];
    __shared__ int   ovf_s[64];
    __shared__ float zh_s[64];
    __shared__ float zn_s[64];
    __shared__ unsigned long long key_s[64];
    __shared__ float s_red[4];
    __shared__ int   work_s;

    const int tid = threadIdx.x;
    const int w = tid >> 6, l = tid & 63;
    const int n0 = blockIdx.x * 64;
    const int b = n0 >> 10, p0 = n0 & 1023;
    const int* cnt  = (const int*)ws + WS_CNT_IOFF;
    const int* cand = (const int*)ws + WS_CAND_IOFF;
    const float* cn = ws + WS_CNORM_OFF;

    if (tid < 64) {   // wave 0: per-query state + prefix scan + work flag
        int c = cnt[n0 + tid];
        int ov = (c > CAND_CAP) ? 1 : 0;
        ovf_s[tid] = ov;
        int cc = (ov || c < 2) ? 0 : c;
        c_s[tid] = cc;
        key_s[tid] = ~0ULL;
        if (cc == 0 && !ov) idx_s[tid] = (int)out[IDX_OFF + n0 + tid];  // filter-resolved
        int v = cc;
#pragma unroll
        for (int off = 1; off < 64; off <<= 1) {
            int u = __shfl_up(v, off, 64);
            if (l >= off) v += u;
        }
        offI[tid] = v;
        unsigned long long ball = __ballot(ov != 0);
        if (tid == 63) work_s = v + (ball ? 1 : 0);
    }

    // stage z tile: [d][q] fp32, float4 coalesced (exact bits); always needed
    {
        const float* zb = z + (size_t)b * EMB_DIM * HW + p0;
        const int q4 = tid & 15, g = tid >> 4;
#pragma unroll 4
        for (int r = 0; r < 16; ++r) {
            int d = r * 16 + g;
            float4 vv = *(const float4*)(zb + (size_t)d * HW + q4 * 4);
            *(float4*)&z_lds[d][q4 * 4] = vv;
        }
    }
    __syncthreads();

    if (work_s != 0) {
        // znorm from z_lds: exact pairwise tree, 2 threads/query (128-d seam)
        float hf0 = 0.0f;
        if (tid < 128) {
            const int q = tid & 63, h = tid >> 6;
            float r[8];
#pragma unroll
            for (int j = 0; j < 8; ++j) {
                float v = z_lds[h * 128 + j][q];
                r[j] = __fmul_rn(v, v);
            }
            for (int i = 8; i < 128; i += 8)
#pragma unroll
                for (int j = 0; j < 8; ++j) {
                    float v = z_lds[h * 128 + i + j][q];
                    r[j] = __fadd_rn(r[j], __fmul_rn(v, v));
                }
            float hf = __fadd_rn(__fadd_rn(__fadd_rn(r[0], r[1]), __fadd_rn(r[2], r[3])),
                                 __fadd_rn(__fadd_rn(r[4], r[5]), __fadd_rn(r[6], r[7])));
            if (h) zh_s[q] = hf; else hf0 = hf;
        }
        __syncthreads();
        if (tid < 64) zn_s[tid] = __fadd_rn(hf0, zh_s[tid]);   // exact fadd(half0, half1)
        __syncthreads();

        // candidate-per-thread exact rescore
        const int C = offI[63];
        for (int t = tid; t < C; t += 256) {
            int lo = 0, hi = 63;
            while (lo < hi) { int mid = (lo + hi) >> 1; if (offI[mid] > t) hi = mid; else lo = mid + 1; }
            const int m = lo;
            const int j = t - (m ? offI[m - 1] : 0);
            const int n = n0 + m;
            const int kk = cand[(size_t)n * CAND_CAP + j];
            const float* r = cb + (size_t)kk * EMB_DIM;
            float dot = 0.0f;
#pragma unroll 8
            for (int d = 0; d < EMB_DIM; ++d)
                dot = fmaf(z_lds[d][m], r[d], dot);
            float t1 = __fadd_rn(zn_s[m], cn[kk]);
            float sv = __fadd_rn(t1, __fmul_rn(-2.0f, dot));
            unsigned ue = __float_as_uint(sv);
            ue = (ue >> 31) ? ~ue : (ue | 0x80000000u);
            atomicMin(&key_s[m], ((unsigned long long)ue << 32) | (unsigned)kk);
        }

        // overflow queries (rare): distributed exact full scan, wave per query
        for (int m = w; m < 64; m += 4) {
            if (!ovf_s[m]) continue;
            const float z2 = zn_s[m];
            float sv = 3.4e38f; int kk = NUM_EMB;
            for (int k0 = l; k0 < NUM_EMB; k0 += 64) {
                const float* r = cb + (size_t)k0 * EMB_DIM;
                float dot = 0.0f;
#pragma unroll 8
                for (int d = 0; d < EMB_DIM; ++d)
                    dot = fmaf(z_lds[d][m], r[d], dot);
                float t1 = __fadd_rn(z2, cn[k0]);
                float s2 = __fadd_rn(t1, __fmul_rn(-2.0f, dot));
                if (s2 < sv) { sv = s2; kk = k0; }   // ascending k: < keeps first
            }
#pragma unroll
            for (int off = 32; off; off >>= 1) {
                float osv = __shfl_xor(sv, off, 64);
                int   okk = __shfl_xor(kk, off, 64);
                if (osv < sv || (osv == sv && okk < kk)) { sv = osv; kk = okk; }
            }
            if (l == 0) {
                unsigned ue = __float_as_uint(sv);
                ue = (ue >> 31) ? ~ue : (ue | 0x80000000u);
                key_s[m] = ((unsigned long long)ue << 32) | (unsigned)kk;
            }
        }
        __syncthreads();
        if (tid < 64 && (c_s[tid] > 0 || ovf_s[tid])) {
            int kk = (int)(unsigned)(key_s[tid] & 0xFFFFFFFFULL);
            idx_s[tid] = kk;
            out[IDX_OFF + n0 + tid] = (float)kk;
        }
        __syncthreads();
    }

    // ---- gather phase: identical per-thread arithmetic/order to the old
    //      k_gather (d = d0 + cgrp*16 + h*8 + j0 == old j 0..15 sequence);
    //      cb rows via half-panel s_half, zv from z_lds ----
    const int p    = tid & 63;
    const int cgrp = tid >> 6;
    const int row  = tid >> 2;
    const int q4g  = tid & 3;
    float* orow = out + (size_t)b * EMB_DIM * HW + p0 + p;

    float acc = 0.0f;
#pragma unroll 1
    for (int d0 = 0; d0 < EMB_DIM; d0 += 64) {
        const float* cr = cb + (size_t)idx_s[row] * EMB_DIM + d0;
#pragma unroll 1
        for (int h = 0; h < 2; ++h) {
#pragma unroll
            for (int pass = 0; pass < 2; ++pass) {
                int s = q4g + pass * 4;
                int gg = s >> 1, j00 = (s & 1) * 4;
                *(float4*)&s_half[row][gg * 8 + j00] = *(const float4*)(cr + gg * 16 + h * 8 + j00);
            }
            __syncthreads();
#pragma unroll
            for (int j0 = 0; j0 < 8; ++j0) {
                int c = cgrp * 16 + h * 8 + j0;
                float zq = s_half[p][cgrp * 8 + j0];
                float zv = z_lds[d0 + c][p];
                float d  = zq - zv;
                orow[(size_t)(d0 + c) * HW] = zv + d;
                acc += d * d;
            }
            __syncthreads();
        }
    }
#pragma unroll
    for (int off = 32; off > 0; off >>= 1) acc += __shfl_down(acc, off, 64);
    if ((tid & 63) == 0) s_red[tid >> 6] = acc;
    __syncthreads();
    if (tid == 0) {
        atomicAdd(ws, s_red[0] + s_red[1] + s_red[2] + s_red[3]);
        __threadfence();
        unsigned old = atomicAdd((unsigned int*)ws + 1, 1u);
        if (old == 511u) {
            float total = atomicAdd(ws, 0.0f);
            out[LOSS_OFF] = 1.25f * (total * (1.0f / 8388608.0f));
        }
    }
}

// ---------------------------------------------------------------------------
extern "C" void kernel_launch(void* const* d_in, const int* in_sizes, int n_in,
                              void* d_out, int out_size, void* d_ws, size_t ws_size,
                              hipStream_t stream) {
    const float* z  = (const float*)d_in[0];
    const float* cb = (const float*)d_in[1];
    float* out = (float*)d_out;
    float* ws  = (float*)d_ws;

    k_prep     <<<132, 256, 0, stream>>>(cb, ws);
    k_filter   <<<512, 256, 0, stream>>>(z, ws, out);
    k_resgather<<<512, 256, 0, stream>>>(z, cb, ws, out);
}